// Round 10
// baseline (174.816 us; speedup 1.0000x reference)
//
#include <hip/hip_runtime.h>
#include <math.h>

#define BB 16
#define NL 4096
#define NH 1024
#define CL 128
#define CHH 256
#define K0 384
#define K1 256
#define CO 256
#define BN_EPS 1e-5f

typedef __attribute__((ext_vector_type(8))) short bfrag;     // 8 bf16
typedef __attribute__((ext_vector_type(4))) float f32x4;
typedef __attribute__((ext_vector_type(4))) unsigned short ushort4b;

__device__ inline unsigned short f2bf(float f) {
    unsigned int u = __builtin_bit_cast(unsigned int, f);
    u += 0x7fffu + ((u >> 16) & 1u);                 // RNE
    return (unsigned short)(u >> 16);
}
__device__ inline float bf2f(unsigned short h) {
    unsigned int u = ((unsigned int)h) << 16;
    return __builtin_bit_cast(float, u);
}

// ---------------------------------------------------------------------------
// setup: weights f32->bf16 + candidate packing (one launch)
// ---------------------------------------------------------------------------
__global__ __launch_bounds__(256) void k_setup(const float* __restrict__ W0s,
                                               unsigned short* __restrict__ Wb0,
                                               const float* __restrict__ W1s,
                                               unsigned short* __restrict__ Wb1,
                                               const float* __restrict__ xyzh,
                                               float4* __restrict__ cand4) {
    int i = blockIdx.x * 256 + threadIdx.x;
    if (i < CO * K0) Wb0[i] = f2bf(W0s[i]);
    if (i < CO * K1) Wb1[i] = f2bf(W1s[i]);
    if (i < BB * NH) {
        float x = xyzh[3 * i], y = xyzh[3 * i + 1], z = xyzh[3 * i + 2];
        float ss = __fadd_rn(__fadd_rn(__fmul_rn(x, x), __fmul_rn(y, y)),
                             __fmul_rn(z, z));
        cand4[i] = make_float4(x, y, z, ss);
    }
}

// ---------------------------------------------------------------------------
// transpose feat_high (B, CH, NH) f32 -> fT (B, NH, CH) bf16
// ---------------------------------------------------------------------------
__global__ __launch_bounds__(256) void k_transpose_fh(const float* __restrict__ fh,
                                                      unsigned short* __restrict__ fT) {
    __shared__ float s[32][33];
    int b = blockIdx.z;
    int c0 = blockIdx.y * 32;
    int m0 = blockIdx.x * 32;
    int tx = threadIdx.x % 32, ty = threadIdx.x / 32;
    const float* src = fh + (size_t)b * CHH * NH;
    unsigned short* dst = fT + (size_t)b * NH * CHH;
#pragma unroll
    for (int j = 0; j < 4; j++)
        s[ty + 8 * j][tx] = src[(size_t)(c0 + ty + 8 * j) * NH + m0 + tx];
    __syncthreads();
    int mi = threadIdx.x >> 3;           // 0..31 point-in-tile
    int cp = threadIdx.x & 7;            // 0..7 channel-pair group
#pragma unroll
    for (int h = 0; h < 2; h++) {
        int ci = (cp + 8 * h) * 2;
        unsigned int o = (unsigned int)f2bf(s[ci][mi]) |
                         ((unsigned int)f2bf(s[ci + 1][mi]) << 16);
        *(unsigned int*)&dst[(size_t)(m0 + mi) * CHH + c0 + ci] = o;
    }
}

// ---------------------------------------------------------------------------
// 3-NN search v7 (unchanged): wave = segment, broadcast LDS reads.
// ---------------------------------------------------------------------------
__global__ __launch_bounds__(256) void k_knn(const float* __restrict__ xyzl,
                                             const float4* __restrict__ cand4,
                                             int* __restrict__ idx,
                                             float* __restrict__ wgt) {
    __shared__ float4 cnd[NH];           // 16 KB
    __shared__ float tls[4][64][3];
    __shared__ int   ils[4][64][3];

    int b = blockIdx.y;
    for (int p = threadIdx.x; p < NH; p += 256)
        cnd[p] = cand4[(size_t)b * NH + p];
    __syncthreads();

    int lane = threadIdx.x & 63;
    int w = threadIdx.x >> 6;            // segment
    int n = blockIdx.x * 64 + lane;

    const float* xl = xyzl + ((size_t)b * NL + n) * 3;
    float l0 = xl[0], l1 = xl[1], l2 = xl[2];
    float a = __fadd_rn(__fadd_rn(__fmul_rn(l0, l0), __fmul_rn(l1, l1)),
                        __fmul_rn(l2, l2));

    float t0 = INFINITY, t1 = INFINITY, t2 = INFINITY;
    int i0 = 0, i1 = 0, i2 = 0;
    int mb = w * 256;
#pragma unroll 8
    for (int j = 0; j < 256; j++) {
        float4 c = cnd[mb + j];          // broadcast read
        int m = mb + j;
        float dot = __fadd_rn(__fadd_rn(__fmul_rn(l0, c.x), __fmul_rn(l1, c.y)),
                              __fmul_rn(l2, c.z));
        float dd = __fsub_rn(__fadd_rn(a, c.w), __fmul_rn(2.0f, dot));
        bool c0 = dd < t0, c1 = dd < t1, c2 = dd < t2;
        float nt0 = fminf(dd, t0);
        float nt1 = __builtin_amdgcn_fmed3f(dd, t0, t1);
        float nt2 = __builtin_amdgcn_fmed3f(dd, t1, t2);
        i2 = c1 ? i1 : (c2 ? m : i2);
        i1 = c0 ? i0 : (c1 ? m : i1);
        i0 = c0 ? m : i0;
        t0 = nt0; t1 = nt1; t2 = nt2;
    }
    tls[w][lane][0] = t0; tls[w][lane][1] = t1; tls[w][lane][2] = t2;
    ils[w][lane][0] = i0; ils[w][lane][1] = i1; ils[w][lane][2] = i2;
    __syncthreads();

    if (threadIdx.x < 64) {
        int p = threadIdx.x;
        float u0 = tls[0][p][0], u1 = tls[0][p][1], u2 = tls[0][p][2];
        int   j0 = ils[0][p][0], j1 = ils[0][p][1], j2 = ils[0][p][2];
#pragma unroll
        for (int sg = 1; sg < 4; sg++) {
#pragma unroll
            for (int e = 0; e < 3; e++) {
                float dd = tls[sg][p][e];
                int m = ils[sg][p][e];
                bool c0 = dd < u0, c1 = dd < u1, c2 = dd < u2;
                u2 = c1 ? u1 : (c2 ? dd : u2);
                j2 = c1 ? j1 : (c2 ? m : j2);
                u1 = c0 ? u0 : (c1 ? dd : u1);
                j1 = c0 ? j0 : (c1 ? m : j1);
                u0 = c0 ? dd : u0;
                j0 = c0 ? m : j0;
            }
        }
        u0 = fmaxf(u0, 0.0f); u1 = fmaxf(u1, 0.0f); u2 = fmaxf(u2, 0.0f);
        float d0 = sqrtf(u0), d1 = sqrtf(u1), d2 = sqrtf(u2);
        float w0 = 1.0f / fmaxf(d0, 1e-8f);
        float w1 = 1.0f / fmaxf(d1, 1e-8f);
        float w2 = 1.0f / fmaxf(d2, 1e-8f);
        float wsum = __fadd_rn(__fadd_rn(w0, w1), w2);
        w0 /= wsum; w1 /= wsum; w2 /= wsum;
        int nn = blockIdx.x * 64 + p;
        size_t base = ((size_t)b * NL + nn) * 3;
        idx[base] = j0; idx[base + 1] = j1; idx[base + 2] = j2;
        wgt[base] = w0; wgt[base + 1] = w1; wgt[base + 2] = w2;
    }
}

// ---------------------------------------------------------------------------
// feat_low (B, CL, NL) f32 -> Xb2[b][n][c] bf16, c in [0,128) (slim layout)
// ---------------------------------------------------------------------------
__global__ __launch_bounds__(256) void k_fl_t(const float* __restrict__ fl,
                                              unsigned short* __restrict__ Xb2) {
    __shared__ unsigned short s[32][68];
    int b = blockIdx.z, c0 = blockIdx.y * 32, n0 = blockIdx.x * 64;
    int tx = threadIdx.x & 63, ty = threadIdx.x >> 6;       // 64 x 4
    const float* src = fl + ((size_t)b * CL + c0) * NL + n0;
#pragma unroll
    for (int i = 0; i < 8; i++) {
        int c = ty * 8 + i;
        s[c][tx] = f2bf(src[(size_t)c * NL + tx]);
    }
    __syncthreads();
    int n = threadIdx.x >> 2, q = threadIdx.x & 3;
    ushort4b o0, o1;
#pragma unroll
    for (int e = 0; e < 4; e++) o0[e] = s[q * 8 + e][n];
#pragma unroll
    for (int e = 0; e < 4; e++) o1[e] = s[q * 8 + 4 + e][n];
    unsigned short* dst = Xb2 + ((size_t)b * NL + n0 + n) * CL + c0 + q * 8;
    *(ushort4b*)dst = o0;
    *(ushort4b*)(dst + 4) = o1;
}

// ---------------------------------------------------------------------------
// staging transforms (bit-identical to old k_bn0 / k_interp chains)
// ---------------------------------------------------------------------------
__device__ inline bfrag bnrelu8(bfrag v, f32x4 s0, f32x4 s1, f32x4 h0, f32x4 h1) {
    bfrag o;
#pragma unroll
    for (int e = 0; e < 4; e++)
        o[e] = (short)f2bf(fmaxf(fmaf(s0[e], bf2f((unsigned short)v[e]), h0[e]), 0.f));
#pragma unroll
    for (int e = 0; e < 4; e++)
        o[4 + e] = (short)f2bf(fmaxf(fmaf(s1[e], bf2f((unsigned short)v[4 + e]), h1[e]), 0.f));
    return o;
}

__device__ inline bfrag interp8(bfrag f0, bfrag f1, bfrag f2,
                                float w0, float w1, float w2) {
    bfrag o;
#pragma unroll
    for (int e = 0; e < 8; e++) {
        float f = __fadd_rn(__fadd_rn(__fmul_rn(w0, bf2f((unsigned short)f0[e])),
                                      __fmul_rn(w1, bf2f((unsigned short)f1[e]))),
                            __fmul_rn(w2, bf2f((unsigned short)f2[e])));
        o[e] = (short)f2bf(f);
    }
    return o;
}

// ---------------------------------------------------------------------------
// Fused MFMA GEMM (round-8 geometry + round-9 fusion):
// Y[b][n][m] = bf16( sum_k W[m][k]*X'[n][k] + bias[m] )
// 128x128 tile, BK=32, 256 thr / 4 waves (2m x 2n of 64x64), XOR-swizzled
// dbuf LDS, XCD-paired 1-D grid (1024 blocks; m-pair 8 apart -> same XCD).
// INTERP: k<256 gathered+interpolated from fT on the fly (exact chain);
//         k>=256 from slim Xb2[n][128]. BN: relu(scale*X+shift) on staging.
// Epilogue: per-block per-channel partial stats to distinct addresses.
// ---------------------------------------------------------------------------
__device__ inline int swz(int r, int cb) {
    return r * 32 + ((cb ^ ((r >> 1) & 3)) << 3);   // short index, 16B blocks
}

template <int K, bool INTERP, bool BN>
__global__ __launch_bounds__(256) void k_gemmb(const unsigned short* __restrict__ X,
                                               const unsigned short* __restrict__ fT,
                                               const int* __restrict__ idx,
                                               const float* __restrict__ wgt,
                                               const unsigned short* __restrict__ Wb,
                                               const float* __restrict__ bias,
                                               const float* __restrict__ bnsc,
                                               const float* __restrict__ bnsh,
                                               unsigned short* __restrict__ Y,
                                               float* __restrict__ psumT,
                                               float* __restrict__ psqT) {
    __shared__ __align__(16) unsigned short sA[2][128 * 32];
    __shared__ __align__(16) unsigned short sB[2][128 * 32];

    int t = blockIdx.x;               // 0..1023
    int xcd = t & 7, ii = t >> 3;     // ii: 0..127 within XCD
    int m0 = (ii & 1) * 128;          // m-pair separated by 8 in t (same XCD)
    int nb = ii >> 1;                 // 0..63
    int n0 = (nb & 31) * 128;
    int b  = xcd * 2 + (nb >> 5);
    int pi2 = (b * 32 + (nb & 31)) * 2;

    int tid = threadIdx.x;
    int lane = tid & 63;
    int wid = tid >> 6;
    int wm = wid >> 1, wn = wid & 1;

    int sr = tid >> 2;                // staging row 0..63 (and +64)
    int scb = tid & 3;                // 16B block within BK row
    int swA0 = swz(sr, scb), swA1 = swz(sr + 64, scb);

    const unsigned short* Wt = Wb + (size_t)m0 * K + scb * 8;

    const int XS = INTERP ? CL : CO;
    const unsigned short* Xr0 = X + ((size_t)b * NL + n0 + sr) * XS + scb * 8;
    const unsigned short* Xr1 = X + ((size_t)b * NL + n0 + sr + 64) * XS + scb * 8;

    // per-thread interp metadata for the 2 owned B rows (hoisted once)
    const unsigned short* fTb = nullptr;
    int a00 = 0, a01 = 0, a02 = 0, a10 = 0, a11 = 0, a12 = 0;
    float w00 = 0, w01 = 0, w02 = 0, w10 = 0, w11 = 0, w12 = 0;
    if (INTERP) {
        fTb = fT + (size_t)b * NH * CHH + scb * 8;
        size_t ib0 = ((size_t)b * NL + n0 + sr) * 3;
        size_t ib1 = ((size_t)b * NL + n0 + sr + 64) * 3;
        a00 = idx[ib0] * CHH; a01 = idx[ib0 + 1] * CHH; a02 = idx[ib0 + 2] * CHH;
        w00 = wgt[ib0]; w01 = wgt[ib0 + 1]; w02 = wgt[ib0 + 2];
        a10 = idx[ib1] * CHH; a11 = idx[ib1 + 1] * CHH; a12 = idx[ib1 + 2] * CHH;
        w10 = wgt[ib1]; w11 = wgt[ib1 + 1]; w12 = wgt[ib1 + 2];
    }

    f32x4 acc[4][4] = {};
    bfrag r00, r01, r02, r10, r11, r12;          // in-flight B staging regs

    auto loadB = [&](int kk) {                   // kk = k-step element base
        if (INTERP) {
            if (kk < CHH) {                      // uniform in kk (see note)
                r00 = *(const bfrag*)&fTb[a00 + kk];
                r01 = *(const bfrag*)&fTb[a01 + kk];
                r02 = *(const bfrag*)&fTb[a02 + kk];
                r10 = *(const bfrag*)&fTb[a10 + kk];
                r11 = *(const bfrag*)&fTb[a11 + kk];
                r12 = *(const bfrag*)&fTb[a12 + kk];
            } else {
                r00 = *(const bfrag*)&Xr0[kk - CHH];
                r10 = *(const bfrag*)&Xr1[kk - CHH];
            }
        } else {
            r00 = *(const bfrag*)&Xr0[kk];
            r10 = *(const bfrag*)&Xr1[kk];
        }
    };
    auto makeB = [&](int kk, bfrag& o0, bfrag& o1) {
        if (INTERP) {
            if (kk < CHH) {
                o0 = interp8(r00, r01, r02, w00, w01, w02);
                o1 = interp8(r10, r11, r12, w10, w11, w12);
            } else { o0 = r00; o1 = r10; }
        } else if (BN) {
            int cg = kk + scb * 8;
            f32x4 sc0 = *(const f32x4*)&bnsc[cg], sc1 = *(const f32x4*)&bnsc[cg + 4];
            f32x4 sh0 = *(const f32x4*)&bnsh[cg], sh1 = *(const f32x4*)&bnsh[cg + 4];
            o0 = bnrelu8(r00, sc0, sc1, sh0, sh1);
            o1 = bnrelu8(r10, sc0, sc1, sh0, sh1);
        } else { o0 = r00; o1 = r10; }
    };

    // prologue: tile 0
    {
        bfrag a0 = *(const bfrag*)&Wt[(size_t)sr * K];
        bfrag a1 = *(const bfrag*)&Wt[(size_t)(sr + 64) * K];
        loadB(0);
        bfrag b0, b1;
        makeB(0, b0, b1);
        *(bfrag*)&sA[0][swA0] = a0;
        *(bfrag*)&sA[0][swA1] = a1;
        *(bfrag*)&sB[0][swA0] = b0;
        *(bfrag*)&sB[0][swA1] = b1;
    }
    __syncthreads();

    const int nkt = K / 32;
    int cur = 0;
#pragma unroll 2
    for (int tt = 0; tt < nkt; tt++) {
        bfrag na0, na1;
        bool more = (tt + 1 < nkt);
        if (more) {
            int kk = (tt + 1) * 32;
            na0 = *(const bfrag*)&Wt[(size_t)sr * K + kk];
            na1 = *(const bfrag*)&Wt[(size_t)(sr + 64) * K + kk];
            loadB(kk);
        }
        bfrag af[4], bf[4];
#pragma unroll
        for (int mi = 0; mi < 4; mi++) {
            int r = wm * 64 + mi * 16 + (lane & 15);
            af[mi] = *(const bfrag*)&sA[cur][swz(r, lane >> 4)];
        }
#pragma unroll
        for (int ni = 0; ni < 4; ni++) {
            int r = wn * 64 + ni * 16 + (lane & 15);
            bf[ni] = *(const bfrag*)&sB[cur][swz(r, lane >> 4)];
        }
#pragma unroll
        for (int mi = 0; mi < 4; mi++)
#pragma unroll
            for (int ni = 0; ni < 4; ni++)
                acc[mi][ni] = __builtin_amdgcn_mfma_f32_16x16x32_bf16(
                    af[mi], bf[ni], acc[mi][ni], 0, 0, 0);
        if (more) {
            bfrag nb0, nb1;
            makeB((tt + 1) * 32, nb0, nb1);
            *(bfrag*)&sA[cur ^ 1][swA0] = na0;
            *(bfrag*)&sA[cur ^ 1][swA1] = na1;
            *(bfrag*)&sB[cur ^ 1][swA0] = nb0;
            *(bfrag*)&sB[cur ^ 1][swA1] = nb1;
            __syncthreads();
            cur ^= 1;
        }
    }

    // C frag: col = lane&15 (n), row = (lane>>4)*4 + j (m)
    int col = lane & 15, rg = (lane >> 4) << 2;
#pragma unroll
    for (int mi = 0; mi < 4; mi++) {
        int m = m0 + wm * 64 + mi * 16 + rg;
        f32x4 bv = *(const f32x4*)&bias[m];
        f32x4 sacc = {0.f, 0.f, 0.f, 0.f}, qacc = {0.f, 0.f, 0.f, 0.f};
#pragma unroll
        for (int ni = 0; ni < 4; ni++) {
            int n = n0 + wn * 64 + ni * 16 + col;
            f32x4 c = acc[mi][ni];
            ushort4b o;
#pragma unroll
            for (int j = 0; j < 4; j++) {
                float sv = c[j] + bv[j];
                o[j] = f2bf(sv);
                sacc[j] += sv;
                qacc[j] += sv * sv;
            }
            *(ushort4b*)&Y[((size_t)b * NL + n) * CO + m] = o;
        }
#pragma unroll
        for (int j = 0; j < 4; j++) {
            float s = sacc[j], q = qacc[j];
#pragma unroll
            for (int off = 1; off < 16; off <<= 1) {
                s += __shfl_xor(s, off, 64);
                q += __shfl_xor(q, off, 64);
            }
            if (col == 0) {
                psumT[(size_t)(m + j) * 1024 + pi2 + wn] = s;
                psqT[(size_t)(m + j) * 1024 + pi2 + wn] = q;
            }
        }
    }
}

// ---------------------------------------------------------------------------
// reduce per-block partials -> scale/shift. One block per channel.
// ---------------------------------------------------------------------------
__global__ __launch_bounds__(256) void k_fin(const float* __restrict__ psumT,
                                             const float* __restrict__ psqT,
                                             const float* __restrict__ gamma,
                                             const float* __restrict__ beta,
                                             float* __restrict__ scale,
                                             float* __restrict__ shift) {
    int c = blockIdx.x;
    const float* ps = psumT + (size_t)c * 1024;
    const float* pq = psqT + (size_t)c * 1024;
    float s = 0.f, q = 0.f;
    for (int i = threadIdx.x; i < 1024; i += 256) { s += ps[i]; q += pq[i]; }
#pragma unroll
    for (int off = 1; off < 64; off <<= 1) {
        s += __shfl_xor(s, off, 64);
        q += __shfl_xor(q, off, 64);
    }
    __shared__ float ls[4], lq[4];
    if ((threadIdx.x & 63) == 0) { ls[threadIdx.x >> 6] = s; lq[threadIdx.x >> 6] = q; }
    __syncthreads();
    if (threadIdx.x == 0) {
        float S = ls[0] + ls[1] + ls[2] + ls[3];
        float Q = lq[0] + lq[1] + lq[2] + lq[3];
        float N = (float)(BB * NL);
        float mean = S / N;
        float var = Q / N - mean * mean;
        float sc = gamma[c] / sqrtf(var + BN_EPS);
        scale[c] = sc;
        shift[c] = beta[c] - mean * sc;
    }
}

// ---------------------------------------------------------------------------
// final: read y1 bf16 [b][n][m], BN1+ReLU, transpose-write f32 out [b][m][n]
// ---------------------------------------------------------------------------
__global__ __launch_bounds__(256) void k_out(const unsigned short* __restrict__ y1,
                                             const float* __restrict__ scale,
                                             const float* __restrict__ shift,
                                             float* __restrict__ out) {
    __shared__ float s[64][65];
    int b = blockIdx.z, m0 = blockIdx.y * 64, n0 = blockIdx.x * 64;
    int r = threadIdx.x >> 3;            // 0..31
    int mq = (threadIdx.x & 7) * 8;      // 0..56
#pragma unroll
    for (int it = 0; it < 2; it++) {
        int row = r + it * 32;
        bfrag v = *(const bfrag*)&y1[((size_t)b * NL + n0 + row) * CO + m0 + mq];
#pragma unroll
        for (int e = 0; e < 8; e++) {
            int m = mq + e;
            float f = bf2f((unsigned short)v[e]);
            s[m][row] = fmaxf(fmaf(scale[m0 + m], f, shift[m0 + m]), 0.f);
        }
    }
    __syncthreads();
    int m = threadIdx.x >> 2, nb = (threadIdx.x & 3) * 16;
    float* orow = out + ((size_t)b * CO + m0 + m) * NL + n0 + nb;
#pragma unroll
    for (int i = 0; i < 16; i += 4) {
        float4 v = make_float4(s[m][nb + i], s[m][nb + i + 1],
                               s[m][nb + i + 2], s[m][nb + i + 3]);
        *(float4*)&orow[i] = v;
    }
}

// ---------------------------------------------------------------------------
extern "C" void kernel_launch(void* const* d_in, const int* in_sizes, int n_in,
                              void* d_out, int out_size, void* d_ws, size_t ws_size,
                              hipStream_t stream) {
    const float* xyz_low   = (const float*)d_in[0];
    const float* xyz_high  = (const float*)d_in[1];
    const float* feat_low  = (const float*)d_in[2];
    const float* feat_high = (const float*)d_in[3];
    const float* W0  = (const float*)d_in[4];
    const float* b0  = (const float*)d_in[5];
    const float* g0  = (const float*)d_in[6];
    const float* be0 = (const float*)d_in[7];
    const float* W1  = (const float*)d_in[8];
    const float* b1  = (const float*)d_in[9];
    const float* g1  = (const float*)d_in[10];
    const float* be1 = (const float*)d_in[11];
    float* out = (float*)d_out;

    char* ws = (char*)d_ws;
    // [Xb2 16MB][y0 32MB][y1 32MB (fT 16MB aliases start; dead before gemm1)]
    unsigned short* Xb2 = (unsigned short*)ws;
    unsigned short* y0  = (unsigned short*)(ws + ((size_t)16 << 20));
    unsigned short* y1  = (unsigned short*)(ws + ((size_t)48 << 20));
    unsigned short* fT  = (unsigned short*)(ws + ((size_t)48 << 20));
    char* tail          = ws + ((size_t)80 << 20);
    int*    idx   = (int*)tail;                       // 768 KB
    float*  wgt   = (float*)(tail + 786432);          // 768 KB
    float4* cand4 = (float4*)(tail + 2 * 786432);     // 256 KB
    unsigned short* Wb0 = (unsigned short*)(tail + 2 * 786432 + 262144);
    unsigned short* Wb1 = Wb0 + CO * K0;              // +192 KB
    char* tail2   = (char*)(Wb1 + CO * K1);           // +128 KB
    float* psumT0 = (float*)tail2;                    // 1 MB  [256][1024]
    float* psqT0  = psumT0 + 256 * 1024;              // 1 MB
    float* psumT1 = psqT0 + 256 * 1024;               // 1 MB
    float* psqT1  = psumT1 + 256 * 1024;              // 1 MB
    float* prm    = psqT1 + 256 * 1024;
    float* scale0 = prm,        *shift0 = prm + 256;
    float* scale1 = prm + 512,  *shift1 = prm + 768;

    k_setup<<<(CO * K0 + 255) / 256, 256, 0, stream>>>(W0, Wb0, W1, Wb1,
                                                       xyz_high, cand4);
    k_transpose_fh<<<dim3(NH / 32, CHH / 32, BB), 256, 0, stream>>>(feat_high, fT);
    k_knn<<<dim3(NL / 64, BB), 256, 0, stream>>>(xyz_low, cand4, idx, wgt);
    k_fl_t<<<dim3(NL / 64, CL / 32, BB), 256, 0, stream>>>(feat_low, Xb2);

    k_gemmb<K0, true, false><<<1024, 256, 0, stream>>>(
        Xb2, fT, idx, wgt, Wb0, b0, nullptr, nullptr, y0, psumT0, psqT0);
    k_fin<<<256, 256, 0, stream>>>(psumT0, psqT0, g0, be0, scale0, shift0);
    k_gemmb<K1, false, true><<<1024, 256, 0, stream>>>(
        y0, nullptr, nullptr, nullptr, Wb1, b1, scale0, shift0, y1, psumT1, psqT1);
    k_fin<<<256, 256, 0, stream>>>(psumT1, psqT1, g1, be1, scale1, shift1);
    k_out<<<dim3(NL / 64, CO / 64, BB), 256, 0, stream>>>(y1, scale1, shift1, out);
}

// Round 11
// 171.299 us; speedup vs baseline: 1.0205x; 1.0205x over previous
//
#include <hip/hip_runtime.h>
#include <math.h>

#define BB 16
#define NL 4096
#define NH 1024
#define CL 128
#define CHH 256
#define K0 384
#define K1 256
#define CO 256
#define BN_EPS 1e-5f

typedef __attribute__((ext_vector_type(8))) short bfrag;     // 8 bf16
typedef __attribute__((ext_vector_type(4))) float f32x4;
typedef __attribute__((ext_vector_type(4))) unsigned short ushort4b;

__device__ inline unsigned short f2bf(float f) {
    unsigned int u = __builtin_bit_cast(unsigned int, f);
    u += 0x7fffu + ((u >> 16) & 1u);                 // RNE
    return (unsigned short)(u >> 16);
}
__device__ inline float bf2f(unsigned short h) {
    unsigned int u = ((unsigned int)h) << 16;
    return __builtin_bit_cast(float, u);
}

// ---------------------------------------------------------------------------
// setup: weights f32->bf16 + candidate packing (one launch)
// ---------------------------------------------------------------------------
__global__ __launch_bounds__(256) void k_setup(const float* __restrict__ W0s,
                                               unsigned short* __restrict__ Wb0,
                                               const float* __restrict__ W1s,
                                               unsigned short* __restrict__ Wb1,
                                               const float* __restrict__ xyzh,
                                               float4* __restrict__ cand4) {
    int i = blockIdx.x * 256 + threadIdx.x;
    if (i < CO * K0) Wb0[i] = f2bf(W0s[i]);
    if (i < CO * K1) Wb1[i] = f2bf(W1s[i]);
    if (i < BB * NH) {
        float x = xyzh[3 * i], y = xyzh[3 * i + 1], z = xyzh[3 * i + 2];
        float ss = __fadd_rn(__fadd_rn(__fmul_rn(x, x), __fmul_rn(y, y)),
                             __fmul_rn(z, z));
        cand4[i] = make_float4(x, y, z, ss);
    }
}

// ---------------------------------------------------------------------------
// transpose feat_high (B, CH, NH) f32 -> fT (B, NH, CH) bf16
// ---------------------------------------------------------------------------
__global__ __launch_bounds__(256) void k_transpose_fh(const float* __restrict__ fh,
                                                      unsigned short* __restrict__ fT) {
    __shared__ float s[32][33];
    int b = blockIdx.z;
    int c0 = blockIdx.y * 32;
    int m0 = blockIdx.x * 32;
    int tx = threadIdx.x % 32, ty = threadIdx.x / 32;
    const float* src = fh + (size_t)b * CHH * NH;
    unsigned short* dst = fT + (size_t)b * NH * CHH;
#pragma unroll
    for (int j = 0; j < 4; j++)
        s[ty + 8 * j][tx] = src[(size_t)(c0 + ty + 8 * j) * NH + m0 + tx];
    __syncthreads();
    int mi = threadIdx.x >> 3;           // 0..31 point-in-tile
    int cp = threadIdx.x & 7;            // 0..7 channel-pair group
#pragma unroll
    for (int h = 0; h < 2; h++) {
        int ci = (cp + 8 * h) * 2;
        unsigned int o = (unsigned int)f2bf(s[ci][mi]) |
                         ((unsigned int)f2bf(s[ci + 1][mi]) << 16);
        *(unsigned int*)&dst[(size_t)(m0 + mi) * CHH + c0 + ci] = o;
    }
}

// ---------------------------------------------------------------------------
// 3-NN search v7 (unchanged): wave = segment, broadcast LDS reads.
// ---------------------------------------------------------------------------
__global__ __launch_bounds__(256) void k_knn(const float* __restrict__ xyzl,
                                             const float4* __restrict__ cand4,
                                             int* __restrict__ idx,
                                             float* __restrict__ wgt) {
    __shared__ float4 cnd[NH];           // 16 KB
    __shared__ float tls[4][64][3];
    __shared__ int   ils[4][64][3];

    int b = blockIdx.y;
    for (int p = threadIdx.x; p < NH; p += 256)
        cnd[p] = cand4[(size_t)b * NH + p];
    __syncthreads();

    int lane = threadIdx.x & 63;
    int w = threadIdx.x >> 6;            // segment
    int n = blockIdx.x * 64 + lane;

    const float* xl = xyzl + ((size_t)b * NL + n) * 3;
    float l0 = xl[0], l1 = xl[1], l2 = xl[2];
    float a = __fadd_rn(__fadd_rn(__fmul_rn(l0, l0), __fmul_rn(l1, l1)),
                        __fmul_rn(l2, l2));

    float t0 = INFINITY, t1 = INFINITY, t2 = INFINITY;
    int i0 = 0, i1 = 0, i2 = 0;
    int mb = w * 256;
#pragma unroll 8
    for (int j = 0; j < 256; j++) {
        float4 c = cnd[mb + j];          // broadcast read
        int m = mb + j;
        float dot = __fadd_rn(__fadd_rn(__fmul_rn(l0, c.x), __fmul_rn(l1, c.y)),
                              __fmul_rn(l2, c.z));
        float dd = __fsub_rn(__fadd_rn(a, c.w), __fmul_rn(2.0f, dot));
        bool c0 = dd < t0, c1 = dd < t1, c2 = dd < t2;
        float nt0 = fminf(dd, t0);
        float nt1 = __builtin_amdgcn_fmed3f(dd, t0, t1);
        float nt2 = __builtin_amdgcn_fmed3f(dd, t1, t2);
        i2 = c1 ? i1 : (c2 ? m : i2);
        i1 = c0 ? i0 : (c1 ? m : i1);
        i0 = c0 ? m : i0;
        t0 = nt0; t1 = nt1; t2 = nt2;
    }
    tls[w][lane][0] = t0; tls[w][lane][1] = t1; tls[w][lane][2] = t2;
    ils[w][lane][0] = i0; ils[w][lane][1] = i1; ils[w][lane][2] = i2;
    __syncthreads();

    if (threadIdx.x < 64) {
        int p = threadIdx.x;
        float u0 = tls[0][p][0], u1 = tls[0][p][1], u2 = tls[0][p][2];
        int   j0 = ils[0][p][0], j1 = ils[0][p][1], j2 = ils[0][p][2];
#pragma unroll
        for (int sg = 1; sg < 4; sg++) {
#pragma unroll
            for (int e = 0; e < 3; e++) {
                float dd = tls[sg][p][e];
                int m = ils[sg][p][e];
                bool c0 = dd < u0, c1 = dd < u1, c2 = dd < u2;
                u2 = c1 ? u1 : (c2 ? dd : u2);
                j2 = c1 ? j1 : (c2 ? m : j2);
                u1 = c0 ? u0 : (c1 ? dd : u1);
                j1 = c0 ? j0 : (c1 ? m : j1);
                u0 = c0 ? dd : u0;
                j0 = c0 ? m : j0;
            }
        }
        u0 = fmaxf(u0, 0.0f); u1 = fmaxf(u1, 0.0f); u2 = fmaxf(u2, 0.0f);
        float d0 = sqrtf(u0), d1 = sqrtf(u1), d2 = sqrtf(u2);
        float w0 = 1.0f / fmaxf(d0, 1e-8f);
        float w1 = 1.0f / fmaxf(d1, 1e-8f);
        float w2 = 1.0f / fmaxf(d2, 1e-8f);
        float wsum = __fadd_rn(__fadd_rn(w0, w1), w2);
        w0 /= wsum; w1 /= wsum; w2 /= wsum;
        int nn = blockIdx.x * 64 + p;
        size_t base = ((size_t)b * NL + nn) * 3;
        idx[base] = j0; idx[base + 1] = j1; idx[base + 2] = j2;
        wgt[base] = w0; wgt[base + 1] = w1; wgt[base + 2] = w2;
    }
}

// ---------------------------------------------------------------------------
// feat_low (B, CL, NL) f32 -> Xb2[b][n][c] bf16, c in [0,128) (slim layout)
// ---------------------------------------------------------------------------
__global__ __launch_bounds__(256) void k_fl_t(const float* __restrict__ fl,
                                              unsigned short* __restrict__ Xb2) {
    __shared__ unsigned short s[32][68];
    int b = blockIdx.z, c0 = blockIdx.y * 32, n0 = blockIdx.x * 64;
    int tx = threadIdx.x & 63, ty = threadIdx.x >> 6;       // 64 x 4
    const float* src = fl + ((size_t)b * CL + c0) * NL + n0;
#pragma unroll
    for (int i = 0; i < 8; i++) {
        int c = ty * 8 + i;
        s[c][tx] = f2bf(src[(size_t)c * NL + tx]);
    }
    __syncthreads();
    int n = threadIdx.x >> 2, q = threadIdx.x & 3;
    ushort4b o0, o1;
#pragma unroll
    for (int e = 0; e < 4; e++) o0[e] = s[q * 8 + e][n];
#pragma unroll
    for (int e = 0; e < 4; e++) o1[e] = s[q * 8 + 4 + e][n];
    unsigned short* dst = Xb2 + ((size_t)b * NL + n0 + n) * CL + c0 + q * 8;
    *(ushort4b*)dst = o0;
    *(ushort4b*)(dst + 4) = o1;
}

// ---------------------------------------------------------------------------
// staging transforms (bit-identical chains)
// ---------------------------------------------------------------------------
__device__ inline bfrag bnrelu8(bfrag v, f32x4 s0, f32x4 s1, f32x4 h0, f32x4 h1) {
    bfrag o;
#pragma unroll
    for (int e = 0; e < 4; e++)
        o[e] = (short)f2bf(fmaxf(fmaf(s0[e], bf2f((unsigned short)v[e]), h0[e]), 0.f));
#pragma unroll
    for (int e = 0; e < 4; e++)
        o[4 + e] = (short)f2bf(fmaxf(fmaf(s1[e], bf2f((unsigned short)v[4 + e]), h1[e]), 0.f));
    return o;
}

__device__ inline bfrag interp8(bfrag f0, bfrag f1, bfrag f2,
                                float w0, float w1, float w2) {
    bfrag o;
#pragma unroll
    for (int e = 0; e < 8; e++) {
        float f = __fadd_rn(__fadd_rn(__fmul_rn(w0, bf2f((unsigned short)f0[e])),
                                      __fmul_rn(w1, bf2f((unsigned short)f1[e]))),
                            __fmul_rn(w2, bf2f((unsigned short)f2[e])));
        o[e] = (short)f2bf(f);
    }
    return o;
}

// ---------------------------------------------------------------------------
// Barrier-free-k-loop fused GEMM:
// Y[b][n][m] = bf16( sum_k W[m][k]*X'[n][k] + bias[m] )
// BM=256 (all of M), BN=64, full-K B-tile staged ONCE in LDS (+1-block row
// pad -> conflict-free b128 reads), single barrier, then pure ds_read+MFMA
// k-loop with W fragments loaded directly from global (L2-resident, 16 full
// 64B lines per af load, prefetched 1 k-step ahead). 256 thr / 4 waves,
// each wave: 64m x 64n. Grid 1024 = 16 b x 64 n-panels, XCD-interleaved.
// INTERP: k<256 gathered+interpolated from fT (exact chain); k>=256 from
// slim Xb2. BN: relu(scale*X+shift) on staging. Epilogue: bias + bf16 store
// + per-block per-channel partial stats to distinct addresses (slot=block).
// ---------------------------------------------------------------------------
template <int K, bool INTERP, bool BN>
__global__ __launch_bounds__(256) void k_gemmt(const unsigned short* __restrict__ X,
                                               const unsigned short* __restrict__ fT,
                                               const int* __restrict__ idx,
                                               const float* __restrict__ wgt,
                                               const unsigned short* __restrict__ Wb,
                                               const float* __restrict__ bias,
                                               const float* __restrict__ bnsc,
                                               const float* __restrict__ bnsh,
                                               unsigned short* __restrict__ Y,
                                               float* __restrict__ psumT,
                                               float* __restrict__ psqT) {
    constexpr int NBLK = K / 8;            // 16B blocks per row (48 or 32)
    constexpr int LROW8 = (NBLK + 1) * 8;  // padded row length in shorts
    __shared__ __align__(16) unsigned short sB[64 * LROW8];

    int t = blockIdx.x;                    // 0..1023
    int xcd = t & 7, ii = t >> 3;          // ii 0..127
    int b  = xcd * 2 + (ii >> 6);
    int n0 = (ii & 63) * 64;

    int tid = threadIdx.x;
    int lane = tid & 63;
    int wid = tid >> 6;                    // 0..3 -> m-range wid*64

    // ---------------- stage full B tile (one pass, then one barrier) -------
    {
        int r = tid >> 2, c4 = tid & 3;    // row 0..63, block phase 0..3
        int nrow = n0 + r;
        unsigned short* srow = &sB[r * LROW8];
        if (INTERP) {
            size_t ib = ((size_t)b * NL + nrow) * 3;
            int a0 = idx[ib] * CHH, a1 = idx[ib + 1] * CHH, a2 = idx[ib + 2] * CHH;
            float w0 = wgt[ib], w1 = wgt[ib + 1], w2 = wgt[ib + 2];
            const unsigned short* fTb = fT + (size_t)b * NH * CHH;
            const unsigned short* xr = X + ((size_t)b * NL + nrow) * CL;
#pragma unroll
            for (int j = 0; j < 8; j++) {              // interp blocks (k<256)
                int ke = (c4 + 4 * j) * 8;
                bfrag f0 = *(const bfrag*)&fTb[a0 + ke];
                bfrag f1 = *(const bfrag*)&fTb[a1 + ke];
                bfrag f2 = *(const bfrag*)&fTb[a2 + ke];
                *(bfrag*)&srow[ke] = interp8(f0, f1, f2, w0, w1, w2);
            }
#pragma unroll
            for (int j = 8; j < NBLK / 4; j++) {       // copy blocks (k>=256)
                int ke = (c4 + 4 * j) * 8;
                *(bfrag*)&srow[ke] = *(const bfrag*)&xr[ke - CHH];
            }
        } else {
            const unsigned short* xr = X + ((size_t)b * NL + nrow) * CO;
#pragma unroll
            for (int j = 0; j < NBLK / 4; j++) {
                int ke = (c4 + 4 * j) * 8;
                bfrag v = *(const bfrag*)&xr[ke];
                if (BN) {
                    f32x4 sc0 = *(const f32x4*)&bnsc[ke], sc1 = *(const f32x4*)&bnsc[ke + 4];
                    f32x4 sh0 = *(const f32x4*)&bnsh[ke], sh1 = *(const f32x4*)&bnsh[ke + 4];
                    v = bnrelu8(v, sc0, sc1, sh0, sh1);
                }
                *(bfrag*)&srow[ke] = v;
            }
        }
    }
    __syncthreads();

    // ---------------- barrier-free k-loop ----------------------------------
    int mrow = wid * 64 + (lane & 15);     // W row for this lane (per mi +16)
    int kcol = (lane >> 4) * 8;            // k sub-offset within 32-k step
    f32x4 acc[4][4] = {};

    bfrag afc[4], afn[4];
#pragma unroll
    for (int mi = 0; mi < 4; mi++)
        afc[mi] = *(const bfrag*)&Wb[(size_t)(mrow + mi * 16) * K + kcol];

    const int nkt = K / 32;
#pragma unroll
    for (int tt = 0; tt < nkt; tt++) {
        if (tt + 1 < nkt) {
            int kb = (tt + 1) * 32 + kcol;
#pragma unroll
            for (int mi = 0; mi < 4; mi++)
                afn[mi] = *(const bfrag*)&Wb[(size_t)(mrow + mi * 16) * K + kb];
        }
        bfrag bf[4];
#pragma unroll
        for (int ni = 0; ni < 4; ni++)
            bf[ni] = *(const bfrag*)&sB[(ni * 16 + (lane & 15)) * LROW8 + tt * 32 + kcol];
#pragma unroll
        for (int mi = 0; mi < 4; mi++)
#pragma unroll
            for (int ni = 0; ni < 4; ni++)
                acc[mi][ni] = __builtin_amdgcn_mfma_f32_16x16x32_bf16(
                    afc[mi], bf[ni], acc[mi][ni], 0, 0, 0);
#pragma unroll
        for (int mi = 0; mi < 4; mi++) afc[mi] = afn[mi];
    }

    // ---------------- epilogue: bias + store + stats partials --------------
    int col = lane & 15, rg = (lane >> 4) << 2;
#pragma unroll
    for (int mi = 0; mi < 4; mi++) {
        int m = wid * 64 + mi * 16 + rg;
        f32x4 bv = *(const f32x4*)&bias[m];
        f32x4 sacc = {0.f, 0.f, 0.f, 0.f}, qacc = {0.f, 0.f, 0.f, 0.f};
#pragma unroll
        for (int ni = 0; ni < 4; ni++) {
            int n = n0 + ni * 16 + col;
            f32x4 c = acc[mi][ni];
            ushort4b o;
#pragma unroll
            for (int j = 0; j < 4; j++) {
                float sv = c[j] + bv[j];
                o[j] = f2bf(sv);
                sacc[j] += sv;
                qacc[j] += sv * sv;
            }
            *(ushort4b*)&Y[((size_t)b * NL + n) * CO + m] = o;
        }
#pragma unroll
        for (int j = 0; j < 4; j++) {
            float s = sacc[j], q = qacc[j];
#pragma unroll
            for (int off = 1; off < 16; off <<= 1) {
                s += __shfl_xor(s, off, 64);
                q += __shfl_xor(q, off, 64);
            }
            if (col == 0) {
                psumT[(size_t)(m + j) * 1024 + t] = s;
                psqT[(size_t)(m + j) * 1024 + t] = q;
            }
        }
    }
}

// ---------------------------------------------------------------------------
// reduce per-block partials -> scale/shift. One block per channel.
// ---------------------------------------------------------------------------
__global__ __launch_bounds__(256) void k_fin(const float* __restrict__ psumT,
                                             const float* __restrict__ psqT,
                                             const float* __restrict__ gamma,
                                             const float* __restrict__ beta,
                                             float* __restrict__ scale,
                                             float* __restrict__ shift) {
    int c = blockIdx.x;
    const float* ps = psumT + (size_t)c * 1024;
    const float* pq = psqT + (size_t)c * 1024;
    float s = 0.f, q = 0.f;
    for (int i = threadIdx.x; i < 1024; i += 256) { s += ps[i]; q += pq[i]; }
#pragma unroll
    for (int off = 1; off < 64; off <<= 1) {
        s += __shfl_xor(s, off, 64);
        q += __shfl_xor(q, off, 64);
    }
    __shared__ float ls[4], lq[4];
    if ((threadIdx.x & 63) == 0) { ls[threadIdx.x >> 6] = s; lq[threadIdx.x >> 6] = q; }
    __syncthreads();
    if (threadIdx.x == 0) {
        float S = ls[0] + ls[1] + ls[2] + ls[3];
        float Q = lq[0] + lq[1] + lq[2] + lq[3];
        float N = (float)(BB * NL);
        float mean = S / N;
        float var = Q / N - mean * mean;
        float sc = gamma[c] / sqrtf(var + BN_EPS);
        scale[c] = sc;
        shift[c] = beta[c] - mean * sc;
    }
}

// ---------------------------------------------------------------------------
// final: read y1 bf16 [b][n][m], BN1+ReLU, transpose-write f32 out [b][m][n]
// ---------------------------------------------------------------------------
__global__ __launch_bounds__(256) void k_out(const unsigned short* __restrict__ y1,
                                             const float* __restrict__ scale,
                                             const float* __restrict__ shift,
                                             float* __restrict__ out) {
    __shared__ float s[64][65];
    int b = blockIdx.z, m0 = blockIdx.y * 64, n0 = blockIdx.x * 64;
    int r = threadIdx.x >> 3;            // 0..31
    int mq = (threadIdx.x & 7) * 8;      // 0..56
#pragma unroll
    for (int it = 0; it < 2; it++) {
        int row = r + it * 32;
        bfrag v = *(const bfrag*)&y1[((size_t)b * NL + n0 + row) * CO + m0 + mq];
#pragma unroll
        for (int e = 0; e < 8; e++) {
            int m = mq + e;
            float f = bf2f((unsigned short)v[e]);
            s[m][row] = fmaxf(fmaf(scale[m0 + m], f, shift[m0 + m]), 0.f);
        }
    }
    __syncthreads();
    int m = threadIdx.x >> 2, nb = (threadIdx.x & 3) * 16;
    float* orow = out + ((size_t)b * CO + m0 + m) * NL + n0 + nb;
#pragma unroll
    for (int i = 0; i < 16; i += 4) {
        float4 v = make_float4(s[m][nb + i], s[m][nb + i + 1],
                               s[m][nb + i + 2], s[m][nb + i + 3]);
        *(float4*)&orow[i] = v;
    }
}

// ---------------------------------------------------------------------------
extern "C" void kernel_launch(void* const* d_in, const int* in_sizes, int n_in,
                              void* d_out, int out_size, void* d_ws, size_t ws_size,
                              hipStream_t stream) {
    const float* xyz_low   = (const float*)d_in[0];
    const float* xyz_high  = (const float*)d_in[1];
    const float* feat_low  = (const float*)d_in[2];
    const float* feat_high = (const float*)d_in[3];
    const float* W0  = (const float*)d_in[4];
    const float* b0  = (const float*)d_in[5];
    const float* g0  = (const float*)d_in[6];
    const float* be0 = (const float*)d_in[7];
    const float* W1  = (const float*)d_in[8];
    const float* b1  = (const float*)d_in[9];
    const float* g1  = (const float*)d_in[10];
    const float* be1 = (const float*)d_in[11];
    float* out = (float*)d_out;

    char* ws = (char*)d_ws;
    // [Xb2 16MB][y0 32MB][y1 32MB (fT 16MB aliases start; dead before gemm1)]
    unsigned short* Xb2 = (unsigned short*)ws;
    unsigned short* y0  = (unsigned short*)(ws + ((size_t)16 << 20));
    unsigned short* y1  = (unsigned short*)(ws + ((size_t)48 << 20));
    unsigned short* fT  = (unsigned short*)(ws + ((size_t)48 << 20));
    char* tail          = ws + ((size_t)80 << 20);
    int*    idx   = (int*)tail;                       // 768 KB
    float*  wgt   = (float*)(tail + 786432);          // 768 KB
    float4* cand4 = (float4*)(tail + 2 * 786432);     // 256 KB
    unsigned short* Wb0 = (unsigned short*)(tail + 2 * 786432 + 262144);
    unsigned short* Wb1 = Wb0 + CO * K0;              // +192 KB
    char* tail2   = (char*)(Wb1 + CO * K1);           // +128 KB
    float* psumT0 = (float*)tail2;                    // 1 MB  [256][1024]
    float* psqT0  = psumT0 + 256 * 1024;              // 1 MB
    float* psumT1 = psqT0 + 256 * 1024;               // 1 MB
    float* psqT1  = psumT1 + 256 * 1024;              // 1 MB
    float* prm    = psqT1 + 256 * 1024;
    float* scale0 = prm,        *shift0 = prm + 256;
    float* scale1 = prm + 512,  *shift1 = prm + 768;

    k_setup<<<(CO * K0 + 255) / 256, 256, 0, stream>>>(W0, Wb0, W1, Wb1,
                                                       xyz_high, cand4);
    k_transpose_fh<<<dim3(NH / 32, CHH / 32, BB), 256, 0, stream>>>(feat_high, fT);
    k_knn<<<dim3(NL / 64, BB), 256, 0, stream>>>(xyz_low, cand4, idx, wgt);
    k_fl_t<<<dim3(NL / 64, CL / 32, BB), 256, 0, stream>>>(feat_low, Xb2);

    k_gemmt<K0, true, false><<<1024, 256, 0, stream>>>(
        Xb2, fT, idx, wgt, Wb0, b0, nullptr, nullptr, y0, psumT0, psqT0);
    k_fin<<<256, 256, 0, stream>>>(psumT0, psqT0, g0, be0, scale0, shift0);
    k_gemmt<K1, false, true><<<1024, 256, 0, stream>>>(
        y0, nullptr, nullptr, nullptr, Wb1, b1, scale0, shift0, y1, psumT1, psqT1);
    k_fin<<<256, 256, 0, stream>>>(psumT1, psqT1, g1, be1, scale1, shift1);
    k_out<<<dim3(NL / 64, CO / 64, BB), 256, 0, stream>>>(y1, scale1, shift1, out);
}

// Round 12
// 146.807 us; speedup vs baseline: 1.1908x; 1.1668x over previous
//
#include <hip/hip_runtime.h>
#include <math.h>

#define BB 16
#define NL 4096
#define NH 1024
#define CL 128
#define CHH 256
#define K0 384
#define K1 256
#define CO 256
#define BN_EPS 1e-5f

typedef __attribute__((ext_vector_type(8))) short bfrag;     // 8 bf16
typedef __attribute__((ext_vector_type(4))) float f32x4;
typedef __attribute__((ext_vector_type(4))) unsigned short ushort4b;

__device__ inline unsigned short f2bf(float f) {
    unsigned int u = __builtin_bit_cast(unsigned int, f);
    u += 0x7fffu + ((u >> 16) & 1u);                 // RNE
    return (unsigned short)(u >> 16);
}
__device__ inline float bf2f(unsigned short h) {
    unsigned int u = ((unsigned int)h) << 16;
    return __builtin_bit_cast(float, u);
}

// ---------------------------------------------------------------------------
// setup: weights f32->bf16 + candidate packing (one launch)
// ---------------------------------------------------------------------------
__global__ __launch_bounds__(256) void k_setup(const float* __restrict__ W0s,
                                               unsigned short* __restrict__ Wb0,
                                               const float* __restrict__ W1s,
                                               unsigned short* __restrict__ Wb1,
                                               const float* __restrict__ xyzh,
                                               float4* __restrict__ cand4) {
    int i = blockIdx.x * 256 + threadIdx.x;
    if (i < CO * K0) Wb0[i] = f2bf(W0s[i]);
    if (i < CO * K1) Wb1[i] = f2bf(W1s[i]);
    if (i < BB * NH) {
        float x = xyzh[3 * i], y = xyzh[3 * i + 1], z = xyzh[3 * i + 2];
        float ss = __fadd_rn(__fadd_rn(__fmul_rn(x, x), __fmul_rn(y, y)),
                             __fmul_rn(z, z));
        cand4[i] = make_float4(x, y, z, ss);
    }
}

// ---------------------------------------------------------------------------
// transpose feat_high (B, CH, NH) f32 -> fT (B, NH, CH) bf16
// ---------------------------------------------------------------------------
__global__ __launch_bounds__(256) void k_transpose_fh(const float* __restrict__ fh,
                                                      unsigned short* __restrict__ fT) {
    __shared__ float s[32][33];
    int b = blockIdx.z;
    int c0 = blockIdx.y * 32;
    int m0 = blockIdx.x * 32;
    int tx = threadIdx.x % 32, ty = threadIdx.x / 32;
    const float* src = fh + (size_t)b * CHH * NH;
    unsigned short* dst = fT + (size_t)b * NH * CHH;
#pragma unroll
    for (int j = 0; j < 4; j++)
        s[ty + 8 * j][tx] = src[(size_t)(c0 + ty + 8 * j) * NH + m0 + tx];
    __syncthreads();
    int mi = threadIdx.x >> 3;           // 0..31 point-in-tile
    int cp = threadIdx.x & 7;            // 0..7 channel-pair group
#pragma unroll
    for (int h = 0; h < 2; h++) {
        int ci = (cp + 8 * h) * 2;
        unsigned int o = (unsigned int)f2bf(s[ci][mi]) |
                         ((unsigned int)f2bf(s[ci + 1][mi]) << 16);
        *(unsigned int*)&dst[(size_t)(m0 + mi) * CHH + c0 + ci] = o;
    }
}

// ---------------------------------------------------------------------------
// 3-NN search v7 (unchanged): wave = segment, broadcast LDS reads.
// ---------------------------------------------------------------------------
__global__ __launch_bounds__(256) void k_knn(const float* __restrict__ xyzl,
                                             const float4* __restrict__ cand4,
                                             int* __restrict__ idx,
                                             float* __restrict__ wgt) {
    __shared__ float4 cnd[NH];           // 16 KB
    __shared__ float tls[4][64][3];
    __shared__ int   ils[4][64][3];

    int b = blockIdx.y;
    for (int p = threadIdx.x; p < NH; p += 256)
        cnd[p] = cand4[(size_t)b * NH + p];
    __syncthreads();

    int lane = threadIdx.x & 63;
    int w = threadIdx.x >> 6;            // segment
    int n = blockIdx.x * 64 + lane;

    const float* xl = xyzl + ((size_t)b * NL + n) * 3;
    float l0 = xl[0], l1 = xl[1], l2 = xl[2];
    float a = __fadd_rn(__fadd_rn(__fmul_rn(l0, l0), __fmul_rn(l1, l1)),
                        __fmul_rn(l2, l2));

    float t0 = INFINITY, t1 = INFINITY, t2 = INFINITY;
    int i0 = 0, i1 = 0, i2 = 0;
    int mb = w * 256;
#pragma unroll 8
    for (int j = 0; j < 256; j++) {
        float4 c = cnd[mb + j];          // broadcast read
        int m = mb + j;
        float dot = __fadd_rn(__fadd_rn(__fmul_rn(l0, c.x), __fmul_rn(l1, c.y)),
                              __fmul_rn(l2, c.z));
        float dd = __fsub_rn(__fadd_rn(a, c.w), __fmul_rn(2.0f, dot));
        bool c0 = dd < t0, c1 = dd < t1, c2 = dd < t2;
        float nt0 = fminf(dd, t0);
        float nt1 = __builtin_amdgcn_fmed3f(dd, t0, t1);
        float nt2 = __builtin_amdgcn_fmed3f(dd, t1, t2);
        i2 = c1 ? i1 : (c2 ? m : i2);
        i1 = c0 ? i0 : (c1 ? m : i1);
        i0 = c0 ? m : i0;
        t0 = nt0; t1 = nt1; t2 = nt2;
    }
    tls[w][lane][0] = t0; tls[w][lane][1] = t1; tls[w][lane][2] = t2;
    ils[w][lane][0] = i0; ils[w][lane][1] = i1; ils[w][lane][2] = i2;
    __syncthreads();

    if (threadIdx.x < 64) {
        int p = threadIdx.x;
        float u0 = tls[0][p][0], u1 = tls[0][p][1], u2 = tls[0][p][2];
        int   j0 = ils[0][p][0], j1 = ils[0][p][1], j2 = ils[0][p][2];
#pragma unroll
        for (int sg = 1; sg < 4; sg++) {
#pragma unroll
            for (int e = 0; e < 3; e++) {
                float dd = tls[sg][p][e];
                int m = ils[sg][p][e];
                bool c0 = dd < u0, c1 = dd < u1, c2 = dd < u2;
                u2 = c1 ? u1 : (c2 ? dd : u2);
                j2 = c1 ? j1 : (c2 ? m : j2);
                u1 = c0 ? u0 : (c1 ? dd : u1);
                j1 = c0 ? j0 : (c1 ? m : j1);
                u0 = c0 ? dd : u0;
                j0 = c0 ? m : j0;
            }
        }
        u0 = fmaxf(u0, 0.0f); u1 = fmaxf(u1, 0.0f); u2 = fmaxf(u2, 0.0f);
        float d0 = sqrtf(u0), d1 = sqrtf(u1), d2 = sqrtf(u2);
        float w0 = 1.0f / fmaxf(d0, 1e-8f);
        float w1 = 1.0f / fmaxf(d1, 1e-8f);
        float w2 = 1.0f / fmaxf(d2, 1e-8f);
        float wsum = __fadd_rn(__fadd_rn(w0, w1), w2);
        w0 /= wsum; w1 /= wsum; w2 /= wsum;
        int nn = blockIdx.x * 64 + p;
        size_t base = ((size_t)b * NL + nn) * 3;
        idx[base] = j0; idx[base + 1] = j1; idx[base + 2] = j2;
        wgt[base] = w0; wgt[base + 1] = w1; wgt[base + 2] = w2;
    }
}

// ---------------------------------------------------------------------------
// feat_low (B, CL, NL) f32 -> Xb2[b][n][c] bf16, c in [0,128) (slim layout)
// ---------------------------------------------------------------------------
__global__ __launch_bounds__(256) void k_fl_t(const float* __restrict__ fl,
                                              unsigned short* __restrict__ Xb2) {
    __shared__ unsigned short s[32][68];
    int b = blockIdx.z, c0 = blockIdx.y * 32, n0 = blockIdx.x * 64;
    int tx = threadIdx.x & 63, ty = threadIdx.x >> 6;       // 64 x 4
    const float* src = fl + ((size_t)b * CL + c0) * NL + n0;
#pragma unroll
    for (int i = 0; i < 8; i++) {
        int c = ty * 8 + i;
        s[c][tx] = f2bf(src[(size_t)c * NL + tx]);
    }
    __syncthreads();
    int n = threadIdx.x >> 2, q = threadIdx.x & 3;
    ushort4b o0, o1;
#pragma unroll
    for (int e = 0; e < 4; e++) o0[e] = s[q * 8 + e][n];
#pragma unroll
    for (int e = 0; e < 4; e++) o1[e] = s[q * 8 + 4 + e][n];
    unsigned short* dst = Xb2 + ((size_t)b * NL + n0 + n) * CL + c0 + q * 8;
    *(ushort4b*)dst = o0;
    *(ushort4b*)(dst + 4) = o1;
}

// ---------------------------------------------------------------------------
// staging transforms (bit-identical chains)
// ---------------------------------------------------------------------------
__device__ inline bfrag bnrelu8(bfrag v, f32x4 s0, f32x4 s1, f32x4 h0, f32x4 h1) {
    bfrag o;
#pragma unroll
    for (int e = 0; e < 4; e++)
        o[e] = (short)f2bf(fmaxf(fmaf(s0[e], bf2f((unsigned short)v[e]), h0[e]), 0.f));
#pragma unroll
    for (int e = 0; e < 4; e++)
        o[4 + e] = (short)f2bf(fmaxf(fmaf(s1[e], bf2f((unsigned short)v[4 + e]), h1[e]), 0.f));
    return o;
}

__device__ inline bfrag interp8(bfrag f0, bfrag f1, bfrag f2,
                                float w0, float w1, float w2) {
    bfrag o;
#pragma unroll
    for (int e = 0; e < 8; e++) {
        float f = __fadd_rn(__fadd_rn(__fmul_rn(w0, bf2f((unsigned short)f0[e])),
                                      __fmul_rn(w1, bf2f((unsigned short)f1[e]))),
                            __fmul_rn(w2, bf2f((unsigned short)f2[e])));
        o[e] = (short)f2bf(f);
    }
    return o;
}

// ---------------------------------------------------------------------------
// Fused MFMA GEMM (round-9 chassis + coalesced LDS-transposed epilogue):
// Y[b][n][m] = bf16( sum_k W[m][k]*X'[n][k] + bias[m] )
// BM=256 (all of M: X panel used once), BN=128, BK=32, 512 thr / 8 waves.
// Epilogue: stats from regs, then per wn-half transpose bf16(acc+bias)
// through a 64x(256+8) LDS overlay (reuses sA/sB space) and store Y in
// contiguous 16B chunks -> full 64B lines, no write amplification.
// ---------------------------------------------------------------------------
__device__ inline int swz(int r, int cb) {
    return r * 32 + ((cb ^ ((r >> 1) & 3)) << 3);   // short index, 16B blocks
}

#define EROW 264   // epilogue LDS row stride in shorts (528B, 16B-aligned)

template <int K, bool INTERP, bool BN>
__global__ __launch_bounds__(512) void k_gemmf(const unsigned short* __restrict__ X,
                                               const unsigned short* __restrict__ fT,
                                               const int* __restrict__ idx,
                                               const float* __restrict__ wgt,
                                               const unsigned short* __restrict__ Wb,
                                               const float* __restrict__ bias,
                                               const float* __restrict__ bnsc,
                                               const float* __restrict__ bnsh,
                                               unsigned short* __restrict__ Y,
                                               float* __restrict__ psumT,
                                               float* __restrict__ psqT) {
    __shared__ __align__(16) unsigned short smem[2 * 256 * 32 + 2 * 128 * 32];
    unsigned short (*sA)[256 * 32] = (unsigned short (*)[256 * 32])smem;
    unsigned short (*sB)[128 * 32] = (unsigned short (*)[128 * 32])(smem + 2 * 256 * 32);
    unsigned short* sE = smem;            // epilogue overlay: 64*EROW shorts

    int bt = blockIdx.x;              // 0..511
    int xcd = bt & 7, ii = bt >> 3;   // ii: 0..63 within XCD
    int b  = xcd * 2 + (ii >> 5);     // 2 batches per XCD
    int n0 = (ii & 31) * 128;

    int tid = threadIdx.x;
    int lane = tid & 63;
    int wid = tid >> 6;               // 0..7
    int wm = wid >> 1, wn = wid & 1;  // 4 x 2 waves of 64x64

    int sr = tid >> 2;                // 0..127
    int scb = tid & 3;                // 16B block within BK row
    int swA0 = swz(sr, scb), swA1 = swz(sr + 128, scb);
    int swB = swz(sr, scb);

    const unsigned short* Wt = Wb + scb * 8;
    int nrow = n0 + sr;

    // per-thread interp metadata (hoisted once)
    const unsigned short* fTb;
    int ba0 = 0, ba1 = 0, ba2 = 0;
    float iw0 = 0.f, iw1 = 0.f, iw2 = 0.f;
    if (INTERP) {
        size_t ib = ((size_t)b * NL + nrow) * 3;
        ba0 = idx[ib] * CHH; ba1 = idx[ib + 1] * CHH; ba2 = idx[ib + 2] * CHH;
        iw0 = wgt[ib]; iw1 = wgt[ib + 1]; iw2 = wgt[ib + 2];
        fTb = fT + (size_t)b * NH * CHH;
    }
    const unsigned short* Xrow =
        X + ((size_t)b * NL + nrow) * (INTERP ? CL : CO);

    f32x4 acc[4][4] = {};

    // stage k-step tt into raw regs
    auto stageB = [&](int tt, bfrag& r0, bfrag& r1, bfrag& r2) {
        int cg = tt * 32 + scb * 8;
        if (INTERP) {
            if (cg < CHH) {
                r0 = *(const bfrag*)&fTb[ba0 + cg];
                r1 = *(const bfrag*)&fTb[ba1 + cg];
                r2 = *(const bfrag*)&fTb[ba2 + cg];
            } else {
                r0 = *(const bfrag*)&Xrow[cg - CHH];
            }
        } else {
            r0 = *(const bfrag*)&Xrow[cg];
        }
    };
    auto combineB = [&](int tt, bfrag r0, bfrag r1, bfrag r2) -> bfrag {
        int cg = tt * 32 + scb * 8;
        if (INTERP) {
            if (cg < CHH) return interp8(r0, r1, r2, iw0, iw1, iw2);
            return r0;
        }
        if (BN) {
            f32x4 sc0 = *(const f32x4*)&bnsc[cg], sc1 = *(const f32x4*)&bnsc[cg + 4];
            f32x4 sh0 = *(const f32x4*)&bnsh[cg], sh1 = *(const f32x4*)&bnsh[cg + 4];
            return bnrelu8(r0, sc0, sc1, sh0, sh1);
        }
        return r0;
    };

    // prologue: tile 0
    {
        bfrag a0 = *(const bfrag*)&Wt[(size_t)sr * K];
        bfrag a1 = *(const bfrag*)&Wt[(size_t)(sr + 128) * K];
        bfrag r0, r1, r2;
        stageB(0, r0, r1, r2);
        bfrag bb = combineB(0, r0, r1, r2);
        *(bfrag*)&sA[0][swA0] = a0;
        *(bfrag*)&sA[0][swA1] = a1;
        *(bfrag*)&sB[0][swB] = bb;
    }
    __syncthreads();

    const int nkt = K / 32;
    int cur = 0;
#pragma unroll 2
    for (int tt = 0; tt < nkt; tt++) {
        bfrag na0, na1, r0, r1, r2;
        bool more = (tt + 1 < nkt);
        if (more) {
            int kk = (tt + 1) * 32;
            na0 = *(const bfrag*)&Wt[(size_t)sr * K + kk];
            na1 = *(const bfrag*)&Wt[(size_t)(sr + 128) * K + kk];
            stageB(tt + 1, r0, r1, r2);
        }
        bfrag af[4], bf[4];
#pragma unroll
        for (int mi = 0; mi < 4; mi++) {
            int r = wm * 64 + mi * 16 + (lane & 15);
            af[mi] = *(const bfrag*)&sA[cur][swz(r, lane >> 4)];
        }
#pragma unroll
        for (int ni = 0; ni < 4; ni++) {
            int r = wn * 64 + ni * 16 + (lane & 15);
            bf[ni] = *(const bfrag*)&sB[cur][swz(r, lane >> 4)];
        }
#pragma unroll
        for (int mi = 0; mi < 4; mi++)
#pragma unroll
            for (int ni = 0; ni < 4; ni++)
                acc[mi][ni] = __builtin_amdgcn_mfma_f32_16x16x32_bf16(
                    af[mi], bf[ni], acc[mi][ni], 0, 0, 0);
        if (more) {
            bfrag nb = combineB(tt + 1, r0, r1, r2);
            *(bfrag*)&sA[cur ^ 1][swA0] = na0;
            *(bfrag*)&sA[cur ^ 1][swA1] = na1;
            *(bfrag*)&sB[cur ^ 1][swB] = nb;
            __syncthreads();
            cur ^= 1;
        }
    }

    __syncthreads();                       // retire sA/sB before overlay reuse

    // stats from registers (pre-rounding f32 values = c + bias; unchanged math)
    int col = lane & 15, rg = (lane >> 4) << 2;
    int slot = bt * 2 + wn;
#pragma unroll
    for (int mi = 0; mi < 4; mi++) {
        int m = wm * 64 + mi * 16 + rg;
        f32x4 bv = *(const f32x4*)&bias[m];
        f32x4 sacc = {0.f, 0.f, 0.f, 0.f}, qacc = {0.f, 0.f, 0.f, 0.f};
#pragma unroll
        for (int ni = 0; ni < 4; ni++) {
            f32x4 c = acc[mi][ni];
#pragma unroll
            for (int j = 0; j < 4; j++) {
                float sv = c[j] + bv[j];
                sacc[j] += sv;
                qacc[j] += sv * sv;
            }
        }
#pragma unroll
        for (int j = 0; j < 4; j++) {
            float s = sacc[j], q = qacc[j];
#pragma unroll
            for (int off = 1; off < 16; off <<= 1) {
                s += __shfl_xor(s, off, 64);
                q += __shfl_xor(q, off, 64);
            }
            if (col == 0) {
                psumT[(size_t)(m + j) * 1024 + slot] = s;
                psqT[(size_t)(m + j) * 1024 + slot] = q;
            }
        }
    }

    // two-half LDS transpose + fully-coalesced Y stores
#pragma unroll
    for (int half = 0; half < 2; half++) {
        if (wn == half) {
#pragma unroll
            for (int mi = 0; mi < 4; mi++) {
                int m = wm * 64 + mi * 16 + rg;
                f32x4 bv = *(const f32x4*)&bias[m];
#pragma unroll
                for (int ni = 0; ni < 4; ni++) {
                    int nloc = ni * 16 + col;
                    f32x4 c = acc[mi][ni];
                    ushort4b o;
                    o[0] = f2bf(c[0] + bv[0]); o[1] = f2bf(c[1] + bv[1]);
                    o[2] = f2bf(c[2] + bv[2]); o[3] = f2bf(c[3] + bv[3]);
                    *(ushort4b*)&sE[nloc * EROW + m] = o;
                }
            }
        }
        __syncthreads();
#pragma unroll
        for (int s2 = 0; s2 < 4; s2++) {
            int row = s2 * 16 + (tid >> 5);
            int ch = tid & 31;
            *(bfrag*)&Y[((size_t)b * NL + n0 + half * 64 + row) * CO + ch * 8] =
                *(const bfrag*)&sE[row * EROW + ch * 8];
        }
        __syncthreads();
    }
}

// ---------------------------------------------------------------------------
// reduce per-block partials -> scale/shift. One block per channel.
// ---------------------------------------------------------------------------
__global__ __launch_bounds__(256) void k_fin(const float* __restrict__ psumT,
                                             const float* __restrict__ psqT,
                                             const float* __restrict__ gamma,
                                             const float* __restrict__ beta,
                                             float* __restrict__ scale,
                                             float* __restrict__ shift) {
    int c = blockIdx.x;
    const float* ps = psumT + (size_t)c * 1024;
    const float* pq = psqT + (size_t)c * 1024;
    float s = 0.f, q = 0.f;
    for (int i = threadIdx.x; i < 1024; i += 256) { s += ps[i]; q += pq[i]; }
#pragma unroll
    for (int off = 1; off < 64; off <<= 1) {
        s += __shfl_xor(s, off, 64);
        q += __shfl_xor(q, off, 64);
    }
    __shared__ float ls[4], lq[4];
    if ((threadIdx.x & 63) == 0) { ls[threadIdx.x >> 6] = s; lq[threadIdx.x >> 6] = q; }
    __syncthreads();
    if (threadIdx.x == 0) {
        float S = ls[0] + ls[1] + ls[2] + ls[3];
        float Q = lq[0] + lq[1] + lq[2] + lq[3];
        float N = (float)(BB * NL);
        float mean = S / N;
        float var = Q / N - mean * mean;
        float sc = gamma[c] / sqrtf(var + BN_EPS);
        scale[c] = sc;
        shift[c] = beta[c] - mean * sc;
    }
}

// ---------------------------------------------------------------------------
// final: read y1 bf16 [b][n][m], BN1+ReLU, transpose-write f32 out [b][m][n]
// store pattern: 16 consecutive lanes cover 256B contiguous per m-row
// ---------------------------------------------------------------------------
__global__ __launch_bounds__(256) void k_out(const unsigned short* __restrict__ y1,
                                             const float* __restrict__ scale,
                                             const float* __restrict__ shift,
                                             float* __restrict__ out) {
    __shared__ float s[64][65];
    int b = blockIdx.z, m0 = blockIdx.y * 64, n0 = blockIdx.x * 64;
    int r = threadIdx.x >> 3;            // 0..31
    int mq = (threadIdx.x & 7) * 8;      // 0..56
#pragma unroll
    for (int it = 0; it < 2; it++) {
        int row = r + it * 32;
        bfrag v = *(const bfrag*)&y1[((size_t)b * NL + n0 + row) * CO + m0 + mq];
#pragma unroll
        for (int e = 0; e < 8; e++) {
            int m = mq + e;
            float f = bf2f((unsigned short)v[e]);
            s[m][row] = fmaxf(fmaf(scale[m0 + m], f, shift[m0 + m]), 0.f);
        }
    }
    __syncthreads();
    int ch = threadIdx.x & 15;           // 16B chunk within row
    int mb4 = threadIdx.x >> 4;          // 0..15
#pragma unroll
    for (int it = 0; it < 4; it++) {
        int m = it * 16 + mb4;
        float4 v = make_float4(s[m][ch * 4], s[m][ch * 4 + 1],
                               s[m][ch * 4 + 2], s[m][ch * 4 + 3]);
        *(float4*)&out[((size_t)b * CO + m0 + m) * NL + n0 + ch * 4] = v;
    }
}

// ---------------------------------------------------------------------------
extern "C" void kernel_launch(void* const* d_in, const int* in_sizes, int n_in,
                              void* d_out, int out_size, void* d_ws, size_t ws_size,
                              hipStream_t stream) {
    const float* xyz_low   = (const float*)d_in[0];
    const float* xyz_high  = (const float*)d_in[1];
    const float* feat_low  = (const float*)d_in[2];
    const float* feat_high = (const float*)d_in[3];
    const float* W0  = (const float*)d_in[4];
    const float* b0  = (const float*)d_in[5];
    const float* g0  = (const float*)d_in[6];
    const float* be0 = (const float*)d_in[7];
    const float* W1  = (const float*)d_in[8];
    const float* b1  = (const float*)d_in[9];
    const float* g1  = (const float*)d_in[10];
    const float* be1 = (const float*)d_in[11];
    float* out = (float*)d_out;

    char* ws = (char*)d_ws;
    // [Xb2 16MB][y0 32MB][y1 32MB (fT 8MB aliases start; dead before gemm1)]
    unsigned short* Xb2 = (unsigned short*)ws;
    unsigned short* y0  = (unsigned short*)(ws + ((size_t)16 << 20));
    unsigned short* y1  = (unsigned short*)(ws + ((size_t)48 << 20));
    unsigned short* fT  = (unsigned short*)(ws + ((size_t)48 << 20));
    char* tail          = ws + ((size_t)80 << 20);
    int*    idx   = (int*)tail;                       // 768 KB
    float*  wgt   = (float*)(tail + 786432);          // 768 KB
    float4* cand4 = (float4*)(tail + 2 * 786432);     // 256 KB
    unsigned short* Wb0 = (unsigned short*)(tail + 2 * 786432 + 262144);
    unsigned short* Wb1 = Wb0 + CO * K0;              // +192 KB
    char* tail2   = (char*)(Wb1 + CO * K1);           // +128 KB
    float* psumT0 = (float*)tail2;                    // 1 MB  [256][1024]
    float* psqT0  = psumT0 + 256 * 1024;              // 1 MB
    float* psumT1 = psqT0 + 256 * 1024;               // 1 MB
    float* psqT1  = psumT1 + 256 * 1024;              // 1 MB
    float* prm    = psqT1 + 256 * 1024;
    float* scale0 = prm,        *shift0 = prm + 256;
    float* scale1 = prm + 512,  *shift1 = prm + 768;

    k_setup<<<(CO * K0 + 255) / 256, 256, 0, stream>>>(W0, Wb0, W1, Wb1,
                                                       xyz_high, cand4);
    k_transpose_fh<<<dim3(NH / 32, CHH / 32, BB), 256, 0, stream>>>(feat_high, fT);
    k_knn<<<dim3(NL / 64, BB), 256, 0, stream>>>(xyz_low, cand4, idx, wgt);
    k_fl_t<<<dim3(NL / 64, CL / 32, BB), 256, 0, stream>>>(feat_low, Xb2);

    k_gemmf<K0, true, false><<<512, 512, 0, stream>>>(
        Xb2, fT, idx, wgt, Wb0, b0, nullptr, nullptr, y0, psumT0, psqT0);
    k_fin<<<256, 256, 0, stream>>>(psumT0, psqT0, g0, be0, scale0, shift0);
    k_gemmf<K1, false, true><<<512, 512, 0, stream>>>(
        y0, nullptr, nullptr, nullptr, Wb1, b1, scale0, shift0, y1, psumT1, psqT1);
    k_fin<<<256, 256, 0, stream>>>(psumT1, psqT1, g1, be1, scale1, shift1);
    k_out<<<dim3(NL / 64, CO / 64, BB), 256, 0, stream>>>(y1, scale1, shift1, out);
}